// Round 8
// baseline (462.715 us; speedup 1.0000x reference)
//
#include <hip/hip_runtime.h>
#include <hip/hip_bf16.h>

#define NN 100000
#define EE 1600000

constexpr int SCAN_BLK = 1024;                       // nodes per scan/combine block
constexpr int NB_SCAN  = (NN + SCAN_BLK - 1) / SCAN_BLK;  // 98

// LDS counting-sort CSR build: 8 dst-ranges x 32 edge-chunks
constexpr int NR2 = 8;              // dst ranges (12500 nodes -> 50 KB LDS histogram)
constexpr int RSZ = NN / NR2;       // 12500
constexpr int CH  = 32;             // edge chunks
constexpr int CSZ = EE / CH;        // 50000 edges per chunk (multiple of 4)
constexpr int SCAT_B = CH * NR2;    // 256 scatter blocks in the fused kernel

// ---------------- CSR build (no global atomics) ----------------

__global__ __launch_bounds__(256) void histL_k(const int* __restrict__ ei,
                                               int* __restrict__ CntG) {
    __shared__ int cnt[RSZ];
    int r = blockIdx.x % NR2, c = blockIdx.x / NR2;
    int lo = r * RSZ;
    for (int t = threadIdx.x; t < RSZ; t += 256) cnt[t] = 0;
    __syncthreads();
    const int* __restrict__ dstp = ei + EE;
    int base = c * CSZ;
    int tid = threadIdx.x;
    for (int ii = 0; ii < CSZ; ii += 1024) {
        int off = ii + tid * 4;
        if (off < CSZ) {
            int4 s4 = *(const int4*)&ei[base + off];
            int4 d4 = *(const int4*)&dstp[base + off];
            int dl;
            dl = d4.x - lo; if (dl >= 0 && dl < RSZ && s4.x != d4.x) atomicAdd(&cnt[dl], 1);
            dl = d4.y - lo; if (dl >= 0 && dl < RSZ && s4.y != d4.y) atomicAdd(&cnt[dl], 1);
            dl = d4.z - lo; if (dl >= 0 && dl < RSZ && s4.z != d4.z) atomicAdd(&cnt[dl], 1);
            dl = d4.w - lo; if (dl >= 0 && dl < RSZ && s4.w != d4.w) atomicAdd(&cnt[dl], 1);
        }
    }
    __syncthreads();
    for (int t = threadIdx.x; t < RSZ; t += 256)
        CntG[(size_t)c * NN + lo + t] = cnt[t];
}

// chunk-prefix transform over CntG + per-1024-node partial sums (fused)
__global__ __launch_bounds__(256) void combine_sum_k(int* __restrict__ CntG,
                                                     int* __restrict__ deg,
                                                     int* __restrict__ partials) {
    __shared__ int sh[256];
    int t = threadIdx.x;
    int s_tot = 0;
    #pragma unroll
    for (int k = 0; k < 4; ++k) {
        int d = blockIdx.x * SCAN_BLK + k * 256 + t;
        int run = 0;
        if (d < NN) {
            #pragma unroll 8
            for (int c = 0; c < CH; ++c) {
                int v = CntG[(size_t)c * NN + d];
                CntG[(size_t)c * NN + d] = run;
                run += v;
            }
            deg[d] = run;
        }
        s_tot += run;
    }
    sh[t] = s_tot; __syncthreads();
    for (int off = 128; off > 0; off >>= 1) {
        if (t < off) sh[t] += sh[t + off];
        __syncthreads();
    }
    if (t == 0) partials[blockIdx.x] = sh[0];
}

// rowptr build; the 98-entry partial scan is inlined (cheap per block)
__global__ void scan_final(const int* __restrict__ deg, const int* __restrict__ partials,
                           int* __restrict__ rowptr) {
    __shared__ int sh[256];
    __shared__ int sp[128];
    int t = threadIdx.x;
    if (t < 128) sp[t] = (t < NB_SCAN) ? partials[t] : 0;
    __syncthreads();
    for (int off = 1; off < 128; off <<= 1) {
        int tmp = 0;
        if (t < 128 && t >= off) tmp = sp[t - off];
        __syncthreads();
        if (t < 128) sp[t] += tmp;
        __syncthreads();
    }
    int pref0 = sp[blockIdx.x] - partials[blockIdx.x];   // exclusive prefix of this block

    int base = blockIdx.x * SCAN_BLK + t * 4;
    int v[4]; int s = 0;
    #pragma unroll
    for (int k = 0; k < 4; ++k) { int i = base + k; v[k] = (i < NN) ? deg[i] : 0; s += v[k]; }
    sh[t] = s; __syncthreads();
    for (int off = 1; off < 256; off <<= 1) {
        int tmp = (t >= off) ? sh[t - off] : 0;
        __syncthreads();
        sh[t] += tmp;
        __syncthreads();
    }
    int pref = pref0 + sh[t] - s;
    #pragma unroll
    for (int k = 0; k < 4; ++k) {
        int i = base + k;
        if (i < NN) {
            rowptr[i] = pref; pref += v[k];
            if (i == NN - 1) rowptr[NN] = pref;
        }
    }
}

// ---------------- Fused scatter (CSR col build) || gemm1 ----------------
// Independent work: blocks 0..255 run the LDS scatter, blocks 256.. run the
// layer-1 GEMM (x @ W1 + attention scores). Union'd dynamic LDS (50 KB).

__global__ __launch_bounds__(256) void sg1_k(const int* __restrict__ ei,
                                             const int* __restrict__ CntG,
                                             const int* __restrict__ rowptr,
                                             int* __restrict__ col,
                                             const float* __restrict__ xin,
                                             const float* __restrict__ W,
                                             const float* __restrict__ att,
                                             uint2* __restrict__ Hbf,
                                             float* __restrict__ ssrcA,
                                             float* __restrict__ sdst) {
    extern __shared__ char smem[];
    int tid = threadIdx.x;

    if (blockIdx.x < SCAT_B) {
        // ---- scatter branch ----
        int* cur = (int*)smem;
        int r = blockIdx.x % NR2, c = blockIdx.x / NR2;
        int lo = r * RSZ;
        for (int t = tid; t < RSZ; t += 256)
            cur[t] = rowptr[lo + t] + CntG[(size_t)c * NN + lo + t];
        __syncthreads();
        const int* __restrict__ dstp = ei + EE;
        int base = c * CSZ;
        for (int ii = 0; ii < CSZ; ii += 1024) {
            int off = ii + tid * 4;
            if (off < CSZ) {
                int4 s4 = *(const int4*)&ei[base + off];
                int4 d4 = *(const int4*)&dstp[base + off];
                int dl;
                dl = d4.x - lo; if (dl >= 0 && dl < RSZ && s4.x != d4.x) { int p = atomicAdd(&cur[dl], 1); col[p] = s4.x; }
                dl = d4.y - lo; if (dl >= 0 && dl < RSZ && s4.y != d4.y) { int p = atomicAdd(&cur[dl], 1); col[p] = s4.y; }
                dl = d4.z - lo; if (dl >= 0 && dl < RSZ && s4.z != d4.z) { int p = atomicAdd(&cur[dl], 1); col[p] = s4.z; }
                dl = d4.w - lo; if (dl >= 0 && dl < RSZ && s4.w != d4.w) { int p = atomicAdd(&cur[dl], 1); col[p] = s4.w; }
            }
        }
        return;
    }

    // ---- gemm1 branch: K=128, M=64, H=8, NPB=64 ----
    constexpr int K = 128, M = 64, Hh = 8, NPB = 64;
    constexpr int C   = M / Hh;              // 8
    constexpr int MG  = M / 4;               // 16
    constexpr int K4  = K / 4;               // 32
    constexpr int KC4 = 16;
    constexpr int NCH = K4 / KC4;            // 2

    float4* Wq = (float4*)smem;              // K * MG = 2048 float4 (32 KB)
    float4* Xq = Wq + K * MG;                // NPB * KC4 = 1024 float4 (16 KB)

    const float4* W4 = (const float4*)W;
    for (int i = tid; i < K * MG; i += 256) Wq[i] = W4[i];

    int node0 = (blockIdx.x - SCAT_B) * NPB;
    const float4* x4 = (const float4*)xin;

    int mg = tid % MG, ng = tid / MG;
    int nb = ng * 4;
    float acc[4][4];
    #pragma unroll
    for (int i = 0; i < 4; ++i)
        #pragma unroll
        for (int j = 0; j < 4; ++j) acc[i][j] = 0.f;

    for (int ch = 0; ch < NCH; ++ch) {
        __syncthreads();
        for (int i = tid; i < NPB * KC4; i += 256) {
            int n = i / KC4, k4l = i % KC4;
            int node = node0 + n;
            float4 v = make_float4(0.f, 0.f, 0.f, 0.f);
            if (node < NN) v = x4[(size_t)node * K4 + ch * KC4 + k4l];
            Xq[i] = v;
        }
        __syncthreads();
        #pragma unroll 4
        for (int k4 = 0; k4 < KC4; ++k4) {
            float4 xv[4], wv[4];
            #pragma unroll
            for (int i = 0; i < 4; ++i) xv[i] = Xq[(nb + i) * KC4 + k4];
            int kbase = (ch * KC4 + k4) * 4;
            #pragma unroll
            for (int kk = 0; kk < 4; ++kk) wv[kk] = Wq[(kbase + kk) * MG + mg];
            #pragma unroll
            for (int i = 0; i < 4; ++i) {
                const float* xf = (const float*)&xv[i];
                #pragma unroll
                for (int kk = 0; kk < 4; ++kk) {
                    const float* wf = (const float*)&wv[kk];
                    float xs = xf[kk];
                    acc[i][0] = fmaf(xs, wf[0], acc[i][0]);
                    acc[i][1] = fmaf(xs, wf[1], acc[i][1]);
                    acc[i][2] = fmaf(xs, wf[2], acc[i][2]);
                    acc[i][3] = fmaf(xs, wf[3], acc[i][3]);
                }
            }
        }
    }

    constexpr int TPH = C / 4;               // 2
    int head = mg / TPH;
    int c0   = (mg % TPH) * 4;
    float ad[4], as_[4];
    #pragma unroll
    for (int j = 0; j < 4; ++j) {
        ad[j]  = att[head * 2 * C + c0 + j];
        as_[j] = att[head * 2 * C + C + c0 + j];
    }
    #pragma unroll
    for (int i = 0; i < 4; ++i) {
        int node = node0 + nb + i;
        if (node < NN) {
            unsigned short us[4];
            #pragma unroll
            for (int j = 0; j < 4; ++j) {
                __hip_bfloat16 b = __float2bfloat16(acc[i][j]);
                us[j] = *(unsigned short*)&b;
            }
            uint2 pk;
            pk.x = (unsigned)us[0] | ((unsigned)us[1] << 16);
            pk.y = (unsigned)us[2] | ((unsigned)us[3] << 16);
            Hbf[(size_t)node * MG + mg] = pk;
        }
        float pd = acc[i][0]*ad[0]  + acc[i][1]*ad[1]  + acc[i][2]*ad[2]  + acc[i][3]*ad[3];
        float ps = acc[i][0]*as_[0] + acc[i][1]*as_[1] + acc[i][2]*as_[2] + acc[i][3]*as_[3];
        #pragma unroll
        for (int off = 1; off < TPH; off <<= 1) {
            pd += __shfl_xor(pd, off, 64);
            ps += __shfl_xor(ps, off, 64);
        }
        if ((mg % TPH) == 0 && node < NN) {
            sdst[node * Hh + head]  = pd;
            ssrcA[node * Hh + head] = ps;
        }
    }
}

// ---------------- Fused aggregation + next-layer GEMM ------------------------
// Loop body is the proven round-2 config VERBATIM (one wave/node, U=16,
// unconditional clamped uint2 gathers, gathers-before-exp, col prefetch,
// self-loop prologue). Epilogue replaces the Fb store with the next layer:
// after the acc butterfly every lane holds its channel-quad's reduced sum, so
// the full CT-wide ELU'd row is in-wave. A CP-step shuffle-broadcast + NM
// FMA/lane computes h_next = row @ Wn (Wn is L2-hot, per-step coalesced),
// then next-layer attention scores + bf16 row store (contiguous).

template<int CT, int H, int U, int NM, int NH>
__global__ __launch_bounds__(256) void aggF_k(const int* __restrict__ rowptr, const int* __restrict__ col,
                      const float* __restrict__ sdst, const float* __restrict__ ssrcA,
                      const uint2* __restrict__ Hbf,
                      const float* __restrict__ bias,
                      const float* __restrict__ Wn,
                      const float* __restrict__ attn,
                      unsigned short* __restrict__ Hbf2,
                      float* __restrict__ ssrcA2,
                      float* __restrict__ sdst2) {
    constexpr int C    = CT / H;         // channels per head
    constexpr int CP   = CT / 4;         // lanes covering one row (uint2 = 4 ch)
    constexpr int G    = 64 / CP;        // edge slots per gather instruction
    constexpr int NL   = U / G;          // row gathers in flight per lane
    constexpr int EPEL = (U * H >= 64) ? (U * H) / 64 : 1;   // edges per exp lane
    static_assert(EPEL == 1 || EPEL == 2, "mapping");
    constexpr int NC   = NM / NH;        // next-layer channels per head

    int lane = threadIdx.x & 63;
    int node = blockIdx.x * (blockDim.x >> 6) + (threadIdx.x >> 6);
    if (node >= NN) return;

    int cp = lane % CP;                  // channel quad {4cp..4cp+3}
    int pp = lane / CP;                  // gather slot parity (0..G-1)
    int hh = (4 * cp) / C;               // head of these channels (uniform in quad)
    int eh = lane % H;                   // exp-lane head
    int gb = lane / H;                   // exp-lane base edge slot
    bool elane = (lane < U * H);         // exp-lane mask (EPEL==1 case)

    float sd = elane ? sdst[node * H + eh] : 0.f;

    int start = rowptr[node], end = rowptr[node + 1];

    // ---- virtual self-loop: score + own-row contribution (coalesced) ----
    float dsum = 0.f;
    float e_self = 0.f;
    if (lane < H) {                      // lane == eh, gb == 0
        float ss = ssrcA[node * H + lane];
        float a = sd + ss; a = (a >= 0.f) ? a : 0.2f * a;
        e_self = __expf(a);
        dsum = e_self;
    }
    uint2 hs = Hbf[(size_t)node * CP + cp];
    float exs = __shfl(e_self, hh, 64);
    float4 acc = make_float4(0.f, 0.f, 0.f, 0.f);
    if (pp == 0) {                       // count self row exactly once
        acc.x = exs * __uint_as_float(hs.x << 16);
        acc.y = exs * __uint_as_float(hs.x & 0xffff0000u);
        acc.z = exs * __uint_as_float(hs.y << 16);
        acc.w = exs * __uint_as_float(hs.y & 0xffff0000u);
    }

    // first col chunk
    int cv = node;
    if (start < end) {
        int idx = start + lane;
        if (lane < U && idx < end) cv = col[idx];
    }

    for (int j = start; j < end; j += U) {
        // shuffles of current col chunk (feed both ssrcA and Hbf addressing)
        float s1 = 0.f, s2 = 0.f;
        int b1 = 0, b2 = 0;
        if (EPEL == 2) {
            b1 = __shfl(cv, gb, 64);
            b2 = __shfl(cv, gb + U / 2, 64);
            s1 = ssrcA[b1 * H + eh];     // issued; dead slots clamped to node (cached)
            s2 = ssrcA[b2 * H + eh];
        } else {
            b1 = __shfl(cv, gb, 64);
            if (elane) s1 = ssrcA[b1 * H + eh];
        }

        // issue ALL row gathers back-to-back (depend only on cv)
        uint2 hv[NL];
        #pragma unroll
        for (int t = 0; t < NL; ++t) {
            int se = __shfl(cv, t * G + pp, 64);
            hv[t] = Hbf[(size_t)se * CP + cp];
        }

        // prefetch next col chunk while gathers are in flight
        int jn = j + U;
        int cvN = node;
        if (jn < end) {                  // wave-uniform; after gather issue
            int idx = jn + lane;
            if (lane < U && idx < end) cvN = col[idx];
        }

        // exps (consume ssrcA; Hbf gathers still in flight)
        float e1 = 0.f, e2 = 0.f;
        if (EPEL == 2) {
            float a1 = sd + s1; a1 = (a1 >= 0.f) ? a1 : 0.2f * a1;
            float a2 = sd + s2; a2 = (a2 >= 0.f) ? a2 : 0.2f * a2;
            if (j + gb < end)         e1 = __expf(a1);
            if (j + gb + U / 2 < end) e2 = __expf(a2);
            dsum += e1 + e2;
        } else {
            float a1 = sd + s1; a1 = (a1 >= 0.f) ? a1 : 0.2f * a1;
            if (elane && j + gb < end) { e1 = __expf(a1); dsum += e1; }
        }

        // consume gathers (dead slots have zero weight)
        #pragma unroll
        for (int t = 0; t < NL; ++t) {
            int eidx = t * G + pp;
            float ex;
            if (EPEL == 2)
                ex = __shfl((t * G + G - 1 < U / 2) ? e1 : e2, (eidx & (U / 2 - 1)) * H + hh, 64);
            else
                ex = __shfl(e1, eidx * H + hh, 64);
            float f0 = __uint_as_float(hv[t].x << 16);
            float f1 = __uint_as_float(hv[t].x & 0xffff0000u);
            float f2 = __uint_as_float(hv[t].y << 16);
            float f3 = __uint_as_float(hv[t].y & 0xffff0000u);
            acc.x = fmaf(ex, f0, acc.x);
            acc.y = fmaf(ex, f1, acc.y);
            acc.z = fmaf(ex, f2, acc.z);
            acc.w = fmaf(ex, f3, acc.w);
        }
        cv = cvN;
    }

    // reduce dsum over edge-slot lanes (masked lanes contribute 0)
    #pragma unroll
    for (int off = H; off < 64; off <<= 1) dsum += __shfl_xor(dsum, off, 64);
    float den = __shfl(dsum, hh, 64);    // lane 'hh' holds head hh's full sum
    // reduce acc over gather-slot parities — EVERY lane ends with the full sum
    #pragma unroll
    for (int off = CP; off < 64; off <<= 1) {
        acc.x += __shfl_xor(acc.x, off, 64);
        acc.y += __shfl_xor(acc.y, off, 64);
        acc.z += __shfl_xor(acc.z, off, 64);
        acc.w += __shfl_xor(acc.w, off, 64);
    }

    // ---- this layer's output row (all lanes; pp-duplicated, harmless) ----
    float inv = 1.f / den;
    float4 bv = ((const float4*)bias)[cp];
    float4 v;
    v.x = acc.x * inv + bv.x;
    v.y = acc.y * inv + bv.y;
    v.z = acc.z * inv + bv.z;
    v.w = acc.w * inv + bv.w;
    v.x = (v.x > 0.f) ? v.x : expm1f(v.x);   // ELU(alpha=1)
    v.y = (v.y > 0.f) ? v.y : expm1f(v.y);
    v.z = (v.z > 0.f) ? v.z : expm1f(v.z);
    v.w = (v.w > 0.f) ? v.w : expm1f(v.w);

    // ---- fused next-layer GEMM: lane m computes h_next[m] (m < NM) ----
    float h2 = 0.f;
    #pragma unroll
    for (int q = 0; q < CP; ++q) {
        float fx = __shfl(v.x, q, 64);
        float fy = __shfl(v.y, q, 64);
        float fz = __shfl(v.z, q, 64);
        float fw = __shfl(v.w, q, 64);
        if (lane < NM) {
            h2 = fmaf(fx, Wn[(4 * q + 0) * NM + lane], h2);
            h2 = fmaf(fy, Wn[(4 * q + 1) * NM + lane], h2);
            h2 = fmaf(fz, Wn[(4 * q + 2) * NM + lane], h2);
            h2 = fmaf(fw, Wn[(4 * q + 3) * NM + lane], h2);
        }
    }

    // next-layer attention scores
    int nhead = (lane < NM) ? (lane / NC) : 0;
    int nc    = lane % NC;
    float pd = h2 * attn[nhead * 2 * NC + nc];
    float ps = h2 * attn[nhead * 2 * NC + NC + nc];
    #pragma unroll
    for (int off = 1; off < NC; off <<= 1) {
        pd += __shfl_xor(pd, off, 64);
        ps += __shfl_xor(ps, off, 64);
    }
    if (lane < NM && nc == 0) {
        sdst2[node * NH + nhead]  = pd;
        ssrcA2[node * NH + nhead] = ps;
    }

    // bf16 row store (contiguous 2*NM bytes per node)
    if (lane < NM) {
        __hip_bfloat16 b = __float2bfloat16(h2);
        Hbf2[(size_t)node * NM + lane] = *(unsigned short*)&b;
    }
}

// ---------------- Final aggregation (layer 3, round-2 config) -----------------

template<int CT, int H, int U, bool ELU_OUT>
__global__ __launch_bounds__(256) void agg_k(const int* __restrict__ rowptr, const int* __restrict__ col,
                      const float* __restrict__ sdst, const float* __restrict__ ssrcA,
                      const uint2* __restrict__ Hbf,
                      const float* __restrict__ bias, float* __restrict__ output) {
    constexpr int C    = CT / H;         // channels per head
    constexpr int CP   = CT / 4;         // lanes covering one row (uint2 = 4 ch)
    constexpr int G    = 64 / CP;        // edge slots per gather instruction
    constexpr int NL   = U / G;          // row gathers in flight per lane
    constexpr int EPEL = (U * H >= 64) ? (U * H) / 64 : 1;   // edges per exp lane
    static_assert(EPEL == 1 || EPEL == 2, "mapping");

    int lane = threadIdx.x & 63;
    int node = blockIdx.x * (blockDim.x >> 6) + (threadIdx.x >> 6);
    if (node >= NN) return;

    int cp = lane % CP;                  // channel quad {4cp..4cp+3}
    int pp = lane / CP;                  // gather slot parity (0..G-1)
    int hh = (4 * cp) / C;               // head of these channels (uniform in quad)
    int eh = lane % H;                   // exp-lane head
    int gb = lane / H;                   // exp-lane base edge slot
    bool elane = (lane < U * H);         // exp-lane mask (EPEL==1 case)

    float sd = elane ? sdst[node * H + eh] : 0.f;

    int start = rowptr[node], end = rowptr[node + 1];

    // ---- virtual self-loop: score + own-row contribution (coalesced) ----
    float dsum = 0.f;
    float e_self = 0.f;
    if (lane < H) {                      // lane == eh, gb == 0
        float ss = ssrcA[node * H + lane];
        float a = sd + ss; a = (a >= 0.f) ? a : 0.2f * a;
        e_self = __expf(a);
        dsum = e_self;
    }
    uint2 hs = Hbf[(size_t)node * CP + cp];
    float exs = __shfl(e_self, hh, 64);
    float4 acc = make_float4(0.f, 0.f, 0.f, 0.f);
    if (pp == 0) {                       // count self row exactly once
        acc.x = exs * __uint_as_float(hs.x << 16);
        acc.y = exs * __uint_as_float(hs.x & 0xffff0000u);
        acc.z = exs * __uint_as_float(hs.y << 16);
        acc.w = exs * __uint_as_float(hs.y & 0xffff0000u);
    }

    // first col chunk
    int cv = node;
    if (start < end) {
        int idx = start + lane;
        if (lane < U && idx < end) cv = col[idx];
    }

    for (int j = start; j < end; j += U) {
        float s1 = 0.f, s2 = 0.f;
        int b1 = 0, b2 = 0;
        if (EPEL == 2) {
            b1 = __shfl(cv, gb, 64);
            b2 = __shfl(cv, gb + U / 2, 64);
            s1 = ssrcA[b1 * H + eh];
            s2 = ssrcA[b2 * H + eh];
        } else {
            b1 = __shfl(cv, gb, 64);
            if (elane) s1 = ssrcA[b1 * H + eh];
        }

        uint2 hv[NL];
        #pragma unroll
        for (int t = 0; t < NL; ++t) {
            int se = __shfl(cv, t * G + pp, 64);
            hv[t] = Hbf[(size_t)se * CP + cp];
        }

        int jn = j + U;
        int cvN = node;
        if (jn < end) {
            int idx = jn + lane;
            if (lane < U && idx < end) cvN = col[idx];
        }

        float e1 = 0.f, e2 = 0.f;
        if (EPEL == 2) {
            float a1 = sd + s1; a1 = (a1 >= 0.f) ? a1 : 0.2f * a1;
            float a2 = sd + s2; a2 = (a2 >= 0.f) ? a2 : 0.2f * a2;
            if (j + gb < end)         e1 = __expf(a1);
            if (j + gb + U / 2 < end) e2 = __expf(a2);
            dsum += e1 + e2;
        } else {
            float a1 = sd + s1; a1 = (a1 >= 0.f) ? a1 : 0.2f * a1;
            if (elane && j + gb < end) { e1 = __expf(a1); dsum += e1; }
        }

        #pragma unroll
        for (int t = 0; t < NL; ++t) {
            int eidx = t * G + pp;
            float ex;
            if (EPEL == 2)
                ex = __shfl((t * G + G - 1 < U / 2) ? e1 : e2, (eidx & (U / 2 - 1)) * H + hh, 64);
            else
                ex = __shfl(e1, eidx * H + hh, 64);
            float f0 = __uint_as_float(hv[t].x << 16);
            float f1 = __uint_as_float(hv[t].x & 0xffff0000u);
            float f2 = __uint_as_float(hv[t].y << 16);
            float f3 = __uint_as_float(hv[t].y & 0xffff0000u);
            acc.x = fmaf(ex, f0, acc.x);
            acc.y = fmaf(ex, f1, acc.y);
            acc.z = fmaf(ex, f2, acc.z);
            acc.w = fmaf(ex, f3, acc.w);
        }
        cv = cvN;
    }

    #pragma unroll
    for (int off = H; off < 64; off <<= 1) dsum += __shfl_xor(dsum, off, 64);
    float den = __shfl(dsum, hh, 64);
    #pragma unroll
    for (int off = CP; off < 64; off <<= 1) {
        acc.x += __shfl_xor(acc.x, off, 64);
        acc.y += __shfl_xor(acc.y, off, 64);
        acc.z += __shfl_xor(acc.z, off, 64);
        acc.w += __shfl_xor(acc.w, off, 64);
    }
    if (lane < CP) {
        float inv = 1.f / den;
        float4 bv = ((const float4*)bias)[cp];
        float4 v;
        v.x = acc.x * inv + bv.x;
        v.y = acc.y * inv + bv.y;
        v.z = acc.z * inv + bv.z;
        v.w = acc.w * inv + bv.w;
        if (ELU_OUT) {
            v.x = (v.x > 0.f) ? v.x : expm1f(v.x);
            v.y = (v.y > 0.f) ? v.y : expm1f(v.y);
            v.z = (v.z > 0.f) ? v.z : expm1f(v.z);
            v.w = (v.w > 0.f) ? v.w : expm1f(v.w);
        }
        ((float4*)output)[(size_t)node * CP + cp] = v;
    }
}

// ---------------- launch ----------------

extern "C" void kernel_launch(void* const* d_in, const int* in_sizes, int n_in,
                              void* d_out, int out_size, void* d_ws, size_t ws_size,
                              hipStream_t stream) {
    const float* x    = (const float*)d_in[0];
    const int*   ei   = (const int*)d_in[1];
    const float* W1   = (const float*)d_in[2];
    const float* att1 = (const float*)d_in[3];
    const float* b1   = (const float*)d_in[4];
    const float* W2   = (const float*)d_in[5];
    const float* att2 = (const float*)d_in[6];
    const float* b2   = (const float*)d_in[7];
    const float* W3   = (const float*)d_in[8];
    const float* att3 = (const float*)d_in[9];
    const float* b3   = (const float*)d_in[10];
    float* out = (float*)d_out;

    char* p = (char*)d_ws;
    auto alloc = [&](size_t bytes) -> void* {
        void* r = (void*)p;
        p += (bytes + 255) & ~(size_t)255;
        return r;
    };
    int*   rowptr   = (int*)alloc((NN + 1) * sizeof(int));
    int*   deg      = (int*)alloc(NN * sizeof(int));
    int*   CntG     = (int*)alloc((size_t)CH * NN * sizeof(int));
    int*   partials = (int*)alloc(NB_SCAN * sizeof(int));
    int*   col      = (int*)alloc(EE * sizeof(int));
    float* sdst1    = (float*)alloc((size_t)NN * 8 * sizeof(float));
    float* ssrcA1   = (float*)alloc((size_t)NN * 8 * sizeof(float));
    uint2* Hbf1     = (uint2*)alloc((size_t)NN * 16 * sizeof(uint2));
    float* sdst2    = (float*)alloc((size_t)NN * 8 * sizeof(float));
    float* ssrcA2   = (float*)alloc((size_t)NN * 8 * sizeof(float));
    unsigned short* Hbf2 = (unsigned short*)alloc((size_t)NN * 64 * sizeof(unsigned short));
    float* sdst3    = (float*)alloc((size_t)NN * sizeof(float));
    float* ssrcA3   = (float*)alloc((size_t)NN * sizeof(float));
    unsigned short* Hbf3 = (unsigned short*)alloc((size_t)NN * 32 * sizeof(unsigned short));

    // --- CSR build front (3 dispatches) ---
    histL_k<<<CH * NR2, 256, 0, stream>>>(ei, CntG);
    combine_sum_k<<<NB_SCAN, 256, 0, stream>>>(CntG, deg, partials);
    scan_final<<<NB_SCAN, 256, 0, stream>>>(deg, partials, rowptr);

    // --- scatter || gemm1 (fused, union'd dynamic LDS) ---
    constexpr int SMEM = RSZ * (int)sizeof(int);   // 50000 B >= gemm's 48 KB
    sg1_k<<<SCAT_B + (NN + 63) / 64, 256, SMEM, stream>>>(ei, CntG, rowptr, col,
                                                          x, W1, att1, Hbf1, ssrcA1, sdst1);

    // --- layer 1 agg + fused gemm2 ---
    aggF_k<64, 8, 16, 64, 8><<<(NN + 3) / 4, 256, 0, stream>>>(rowptr, col, sdst1, ssrcA1, Hbf1, b1,
                                                               W2, att2, Hbf2, ssrcA2, sdst2);

    // --- layer 2 agg + fused gemm3 ---
    aggF_k<64, 8, 16, 32, 1><<<(NN + 3) / 4, 256, 0, stream>>>(rowptr, col, sdst2, ssrcA2, (const uint2*)Hbf2, b2,
                                                               W3, att3, Hbf3, ssrcA3, sdst3);

    // --- layer 3 agg -> output ---
    agg_k<32, 1, 32, false><<<(NN + 3) / 4, 256, 0, stream>>>(rowptr, col, sdst3, ssrcA3, (const uint2*)Hbf3,
                                                              b3, out);
}

// Round 9
// 385.506 us; speedup vs baseline: 1.2003x; 1.2003x over previous
//
#include <hip/hip_runtime.h>
#include <hip/hip_bf16.h>

#define NN 100000
#define EE 1600000

constexpr int SCAN_BLK = 1024;                       // nodes per scan/combine block
constexpr int NB_SCAN  = (NN + SCAN_BLK - 1) / SCAN_BLK;  // 98

// LDS counting-sort CSR build: 8 dst-ranges x 32 edge-chunks
constexpr int NR2 = 8;              // dst ranges (12500 nodes -> 50 KB LDS histogram)
constexpr int RSZ = NN / NR2;       // 12500
constexpr int CH  = 32;             // edge chunks
constexpr int CSZ = EE / CH;        // 50000 edges per chunk (multiple of 4)
constexpr int SCAT_B = CH * NR2;    // 256 scatter blocks in the fused kernel

// ---------------- CSR build (no global atomics) ----------------

__global__ __launch_bounds__(256) void histL_k(const int* __restrict__ ei,
                                               int* __restrict__ CntG) {
    __shared__ int cnt[RSZ];
    int r = blockIdx.x % NR2, c = blockIdx.x / NR2;
    int lo = r * RSZ;
    for (int t = threadIdx.x; t < RSZ; t += 256) cnt[t] = 0;
    __syncthreads();
    const int* __restrict__ dstp = ei + EE;
    int base = c * CSZ;
    int tid = threadIdx.x;
    for (int ii = 0; ii < CSZ; ii += 1024) {
        int off = ii + tid * 4;
        if (off < CSZ) {
            int4 s4 = *(const int4*)&ei[base + off];
            int4 d4 = *(const int4*)&dstp[base + off];
            int dl;
            dl = d4.x - lo; if (dl >= 0 && dl < RSZ && s4.x != d4.x) atomicAdd(&cnt[dl], 1);
            dl = d4.y - lo; if (dl >= 0 && dl < RSZ && s4.y != d4.y) atomicAdd(&cnt[dl], 1);
            dl = d4.z - lo; if (dl >= 0 && dl < RSZ && s4.z != d4.z) atomicAdd(&cnt[dl], 1);
            dl = d4.w - lo; if (dl >= 0 && dl < RSZ && s4.w != d4.w) atomicAdd(&cnt[dl], 1);
        }
    }
    __syncthreads();
    for (int t = threadIdx.x; t < RSZ; t += 256)
        CntG[(size_t)c * NN + lo + t] = cnt[t];
}

// chunk-prefix transform over CntG + per-1024-node partial sums (fused)
__global__ __launch_bounds__(256) void combine_sum_k(int* __restrict__ CntG,
                                                     int* __restrict__ deg,
                                                     int* __restrict__ partials) {
    __shared__ int sh[256];
    int t = threadIdx.x;
    int s_tot = 0;
    #pragma unroll
    for (int k = 0; k < 4; ++k) {
        int d = blockIdx.x * SCAN_BLK + k * 256 + t;
        int run = 0;
        if (d < NN) {
            #pragma unroll 8
            for (int c = 0; c < CH; ++c) {
                int v = CntG[(size_t)c * NN + d];
                CntG[(size_t)c * NN + d] = run;
                run += v;
            }
            deg[d] = run;
        }
        s_tot += run;
    }
    sh[t] = s_tot; __syncthreads();
    for (int off = 128; off > 0; off >>= 1) {
        if (t < off) sh[t] += sh[t + off];
        __syncthreads();
    }
    if (t == 0) partials[blockIdx.x] = sh[0];
}

// rowptr build; the 98-entry partial scan is inlined (cheap per block)
__global__ void scan_final(const int* __restrict__ deg, const int* __restrict__ partials,
                           int* __restrict__ rowptr) {
    __shared__ int sh[256];
    __shared__ int sp[128];
    int t = threadIdx.x;
    if (t < 128) sp[t] = (t < NB_SCAN) ? partials[t] : 0;
    __syncthreads();
    for (int off = 1; off < 128; off <<= 1) {
        int tmp = 0;
        if (t < 128 && t >= off) tmp = sp[t - off];
        __syncthreads();
        if (t < 128) sp[t] += tmp;
        __syncthreads();
    }
    int pref0 = sp[blockIdx.x] - partials[blockIdx.x];   // exclusive prefix of this block

    int base = blockIdx.x * SCAN_BLK + t * 4;
    int v[4]; int s = 0;
    #pragma unroll
    for (int k = 0; k < 4; ++k) { int i = base + k; v[k] = (i < NN) ? deg[i] : 0; s += v[k]; }
    sh[t] = s; __syncthreads();
    for (int off = 1; off < 256; off <<= 1) {
        int tmp = (t >= off) ? sh[t - off] : 0;
        __syncthreads();
        sh[t] += tmp;
        __syncthreads();
    }
    int pref = pref0 + sh[t] - s;
    #pragma unroll
    for (int k = 0; k < 4; ++k) {
        int i = base + k;
        if (i < NN) {
            rowptr[i] = pref; pref += v[k];
            if (i == NN - 1) rowptr[NN] = pref;
        }
    }
}

// ---------------- Fused scatter (CSR col build) || gemm1 ----------------
// Verified in round 7. Blocks 0..255 run the LDS scatter; blocks 256.. run the
// layer-1 GEMM (x @ W1 + attention scores). Union'd dynamic LDS (50 KB).

__global__ __launch_bounds__(256) void sg1_k(const int* __restrict__ ei,
                                             const int* __restrict__ CntG,
                                             const int* __restrict__ rowptr,
                                             int* __restrict__ col,
                                             const float* __restrict__ xin,
                                             const float* __restrict__ W,
                                             const float* __restrict__ att,
                                             uint2* __restrict__ Hbf,
                                             float* __restrict__ ssrcA,
                                             float* __restrict__ sdst) {
    extern __shared__ char smem[];
    int tid = threadIdx.x;

    if (blockIdx.x < SCAT_B) {
        // ---- scatter branch ----
        int* cur = (int*)smem;
        int r = blockIdx.x % NR2, c = blockIdx.x / NR2;
        int lo = r * RSZ;
        for (int t = tid; t < RSZ; t += 256)
            cur[t] = rowptr[lo + t] + CntG[(size_t)c * NN + lo + t];
        __syncthreads();
        const int* __restrict__ dstp = ei + EE;
        int base = c * CSZ;
        for (int ii = 0; ii < CSZ; ii += 1024) {
            int off = ii + tid * 4;
            if (off < CSZ) {
                int4 s4 = *(const int4*)&ei[base + off];
                int4 d4 = *(const int4*)&dstp[base + off];
                int dl;
                dl = d4.x - lo; if (dl >= 0 && dl < RSZ && s4.x != d4.x) { int p = atomicAdd(&cur[dl], 1); col[p] = s4.x; }
                dl = d4.y - lo; if (dl >= 0 && dl < RSZ && s4.y != d4.y) { int p = atomicAdd(&cur[dl], 1); col[p] = s4.y; }
                dl = d4.z - lo; if (dl >= 0 && dl < RSZ && s4.z != d4.z) { int p = atomicAdd(&cur[dl], 1); col[p] = s4.z; }
                dl = d4.w - lo; if (dl >= 0 && dl < RSZ && s4.w != d4.w) { int p = atomicAdd(&cur[dl], 1); col[p] = s4.w; }
            }
        }
        return;
    }

    // ---- gemm1 branch: K=128, M=64, H=8, NPB=64 ----
    constexpr int K = 128, M = 64, Hh = 8, NPB = 64;
    constexpr int C   = M / Hh;              // 8
    constexpr int MG  = M / 4;               // 16
    constexpr int K4  = K / 4;               // 32
    constexpr int KC4 = 16;
    constexpr int NCH = K4 / KC4;            // 2

    float4* Wq = (float4*)smem;              // K * MG = 2048 float4 (32 KB)
    float4* Xq = Wq + K * MG;                // NPB * KC4 = 1024 float4 (16 KB)

    const float4* W4 = (const float4*)W;
    for (int i = tid; i < K * MG; i += 256) Wq[i] = W4[i];

    int node0 = (blockIdx.x - SCAT_B) * NPB;
    const float4* x4 = (const float4*)xin;

    int mg = tid % MG, ng = tid / MG;
    int nb = ng * 4;
    float acc[4][4];
    #pragma unroll
    for (int i = 0; i < 4; ++i)
        #pragma unroll
        for (int j = 0; j < 4; ++j) acc[i][j] = 0.f;

    for (int ch = 0; ch < NCH; ++ch) {
        __syncthreads();
        for (int i = tid; i < NPB * KC4; i += 256) {
            int n = i / KC4, k4l = i % KC4;
            int node = node0 + n;
            float4 v = make_float4(0.f, 0.f, 0.f, 0.f);
            if (node < NN) v = x4[(size_t)node * K4 + ch * KC4 + k4l];
            Xq[i] = v;
        }
        __syncthreads();
        #pragma unroll 4
        for (int k4 = 0; k4 < KC4; ++k4) {
            float4 xv[4], wv[4];
            #pragma unroll
            for (int i = 0; i < 4; ++i) xv[i] = Xq[(nb + i) * KC4 + k4];
            int kbase = (ch * KC4 + k4) * 4;
            #pragma unroll
            for (int kk = 0; kk < 4; ++kk) wv[kk] = Wq[(kbase + kk) * MG + mg];
            #pragma unroll
            for (int i = 0; i < 4; ++i) {
                const float* xf = (const float*)&xv[i];
                #pragma unroll
                for (int kk = 0; kk < 4; ++kk) {
                    const float* wf = (const float*)&wv[kk];
                    float xs = xf[kk];
                    acc[i][0] = fmaf(xs, wf[0], acc[i][0]);
                    acc[i][1] = fmaf(xs, wf[1], acc[i][1]);
                    acc[i][2] = fmaf(xs, wf[2], acc[i][2]);
                    acc[i][3] = fmaf(xs, wf[3], acc[i][3]);
                }
            }
        }
    }

    constexpr int TPH = C / 4;               // 2
    int head = mg / TPH;
    int c0   = (mg % TPH) * 4;
    float ad[4], as_[4];
    #pragma unroll
    for (int j = 0; j < 4; ++j) {
        ad[j]  = att[head * 2 * C + c0 + j];
        as_[j] = att[head * 2 * C + C + c0 + j];
    }
    #pragma unroll
    for (int i = 0; i < 4; ++i) {
        int node = node0 + nb + i;
        if (node < NN) {
            unsigned short us[4];
            #pragma unroll
            for (int j = 0; j < 4; ++j) {
                __hip_bfloat16 b = __float2bfloat16(acc[i][j]);
                us[j] = *(unsigned short*)&b;
            }
            uint2 pk;
            pk.x = (unsigned)us[0] | ((unsigned)us[1] << 16);
            pk.y = (unsigned)us[2] | ((unsigned)us[3] << 16);
            Hbf[(size_t)node * MG + mg] = pk;
        }
        float pd = acc[i][0]*ad[0]  + acc[i][1]*ad[1]  + acc[i][2]*ad[2]  + acc[i][3]*ad[3];
        float ps = acc[i][0]*as_[0] + acc[i][1]*as_[1] + acc[i][2]*as_[2] + acc[i][3]*as_[3];
        #pragma unroll
        for (int off = 1; off < TPH; off <<= 1) {
            pd += __shfl_xor(pd, off, 64);
            ps += __shfl_xor(ps, off, 64);
        }
        if ((mg % TPH) == 0 && node < NN) {
            sdst[node * Hh + head]  = pd;
            ssrcA[node * Hh + head] = ps;
        }
    }
}

// ---------------- GEMM (h = x @ W) + per-node attention arrays (layers 2,3) --

template<int K, int M, int H, int NPB>
__global__ __launch_bounds__(256) void gemm_tile(const float* __restrict__ xin,
                          const float* __restrict__ W,
                          const float* __restrict__ att,
                          uint2* __restrict__ Hbf,
                          float* __restrict__ ssrcA,
                          float* __restrict__ sdst) {
    constexpr int C   = M / H;
    constexpr int MG  = M / 4;               // col-groups (4 cols per thread)
    constexpr int NG  = NPB / 4;
    static_assert(MG * NG == 256, "tile mismatch");
    constexpr int K4  = K / 4;
    constexpr int KC4 = (K4 > 16) ? 16 : K4;
    constexpr int NCH = K4 / KC4;

    __shared__ float4 Wq[K * MG];
    __shared__ float4 Xq[NPB * KC4];

    int tid = threadIdx.x;
    const float4* W4 = (const float4*)W;
    for (int i = tid; i < K * MG; i += 256) Wq[i] = W4[i];

    int node0 = blockIdx.x * NPB;
    const float4* x4 = (const float4*)xin;

    int mg = tid % MG, ng = tid / MG;
    int nb = ng * 4;
    float acc[4][4];
    #pragma unroll
    for (int i = 0; i < 4; ++i)
        #pragma unroll
        for (int j = 0; j < 4; ++j) acc[i][j] = 0.f;

    for (int ch = 0; ch < NCH; ++ch) {
        __syncthreads();
        for (int i = tid; i < NPB * KC4; i += 256) {
            int n = i / KC4, k4l = i % KC4;
            int node = node0 + n;
            float4 v = make_float4(0.f, 0.f, 0.f, 0.f);
            if (node < NN) v = x4[(size_t)node * K4 + ch * KC4 + k4l];
            Xq[i] = v;
        }
        __syncthreads();
        #pragma unroll 4
        for (int k4 = 0; k4 < KC4; ++k4) {
            float4 xv[4], wv[4];
            #pragma unroll
            for (int i = 0; i < 4; ++i) xv[i] = Xq[(nb + i) * KC4 + k4];
            int kbase = (ch * KC4 + k4) * 4;
            #pragma unroll
            for (int kk = 0; kk < 4; ++kk) wv[kk] = Wq[(kbase + kk) * MG + mg];
            #pragma unroll
            for (int i = 0; i < 4; ++i) {
                const float* xf = (const float*)&xv[i];
                #pragma unroll
                for (int kk = 0; kk < 4; ++kk) {
                    const float* wf = (const float*)&wv[kk];
                    float xs = xf[kk];
                    acc[i][0] = fmaf(xs, wf[0], acc[i][0]);
                    acc[i][1] = fmaf(xs, wf[1], acc[i][1]);
                    acc[i][2] = fmaf(xs, wf[2], acc[i][2]);
                    acc[i][3] = fmaf(xs, wf[3], acc[i][3]);
                }
            }
        }
    }

    constexpr int TPH = C / 4;               // threads covering one head's cols
    int head = mg / TPH;
    int c0   = (mg % TPH) * 4;
    float ad[4], as_[4];
    #pragma unroll
    for (int j = 0; j < 4; ++j) {
        ad[j]  = att[head * 2 * C + c0 + j];
        as_[j] = att[head * 2 * C + C + c0 + j];
    }
    #pragma unroll
    for (int i = 0; i < 4; ++i) {
        int node = node0 + nb + i;
        if (node < NN) {
            unsigned short us[4];
            #pragma unroll
            for (int j = 0; j < 4; ++j) {
                __hip_bfloat16 b = __float2bfloat16(acc[i][j]);
                us[j] = *(unsigned short*)&b;
            }
            uint2 pk;
            pk.x = (unsigned)us[0] | ((unsigned)us[1] << 16);
            pk.y = (unsigned)us[2] | ((unsigned)us[3] << 16);
            Hbf[(size_t)node * MG + mg] = pk;
        }
        float pd = acc[i][0]*ad[0]  + acc[i][1]*ad[1]  + acc[i][2]*ad[2]  + acc[i][3]*ad[3];
        float ps = acc[i][0]*as_[0] + acc[i][1]*as_[1] + acc[i][2]*as_[2] + acc[i][3]*as_[3];
        #pragma unroll
        for (int off = 1; off < TPH; off <<= 1) {
            pd += __shfl_xor(pd, off, 64);
            ps += __shfl_xor(ps, off, 64);
        }
        if ((mg % TPH) == 0 && node < NN) {
            sdst[node * H + head]  = pd;
            ssrcA[node * H + head] = ps;
        }
    }
}

// ---------------- Aggregation: one wave per node (round-2 config, 59.2 us) ----
// 100K waves, unconditional clamped gathers, predicated-exp masking.

template<int CT, int H, int U, bool ELU_OUT>
__global__ __launch_bounds__(256) void agg_k(const int* __restrict__ rowptr, const int* __restrict__ col,
                      const float* __restrict__ sdst, const float* __restrict__ ssrcA,
                      const uint2* __restrict__ Hbf,
                      const float* __restrict__ bias, float* __restrict__ output) {
    constexpr int C    = CT / H;         // channels per head
    constexpr int CP   = CT / 4;         // lanes covering one row (uint2 = 4 ch)
    constexpr int G    = 64 / CP;        // edge slots per gather instruction
    constexpr int NL   = U / G;          // row gathers in flight per lane
    constexpr int EPEL = (U * H >= 64) ? (U * H) / 64 : 1;   // edges per exp lane
    static_assert(EPEL == 1 || EPEL == 2, "mapping");

    int lane = threadIdx.x & 63;
    int node = blockIdx.x * (blockDim.x >> 6) + (threadIdx.x >> 6);
    if (node >= NN) return;

    int cp = lane % CP;                  // channel quad {4cp..4cp+3}
    int pp = lane / CP;                  // gather slot parity (0..G-1)
    int hh = (4 * cp) / C;               // head of these channels (uniform in quad)
    int eh = lane % H;                   // exp-lane head
    int gb = lane / H;                   // exp-lane base edge slot
    bool elane = (lane < U * H);         // exp-lane mask (EPEL==1 case)

    float sd = elane ? sdst[node * H + eh] : 0.f;

    int start = rowptr[node], end = rowptr[node + 1];

    // ---- virtual self-loop: score + own-row contribution (coalesced) ----
    float dsum = 0.f;
    float e_self = 0.f;
    if (lane < H) {                      // lane == eh, gb == 0
        float ss = ssrcA[node * H + lane];
        float a = sd + ss; a = (a >= 0.f) ? a : 0.2f * a;
        e_self = __expf(a);
        dsum = e_self;
    }
    uint2 hs = Hbf[(size_t)node * CP + cp];
    float exs = __shfl(e_self, hh, 64);
    float4 acc = make_float4(0.f, 0.f, 0.f, 0.f);
    if (pp == 0) {                       // count self row exactly once
        acc.x = exs * __uint_as_float(hs.x << 16);
        acc.y = exs * __uint_as_float(hs.x & 0xffff0000u);
        acc.z = exs * __uint_as_float(hs.y << 16);
        acc.w = exs * __uint_as_float(hs.y & 0xffff0000u);
    }

    // first col chunk
    int cv = node;
    if (start < end) {
        int idx = start + lane;
        if (lane < U && idx < end) cv = col[idx];
    }

    for (int j = start; j < end; j += U) {
        // shuffles of current col chunk (feed both ssrcA and Hbf addressing)
        float s1 = 0.f, s2 = 0.f;
        int b1 = 0, b2 = 0;
        if (EPEL == 2) {
            b1 = __shfl(cv, gb, 64);
            b2 = __shfl(cv, gb + U / 2, 64);
            s1 = ssrcA[b1 * H + eh];     // issued; dead slots clamped to node (cached)
            s2 = ssrcA[b2 * H + eh];
        } else {
            b1 = __shfl(cv, gb, 64);
            if (elane) s1 = ssrcA[b1 * H + eh];
        }

        // issue ALL row gathers back-to-back (depend only on cv)
        uint2 hv[NL];
        #pragma unroll
        for (int t = 0; t < NL; ++t) {
            int se = __shfl(cv, t * G + pp, 64);
            hv[t] = Hbf[(size_t)se * CP + cp];
        }

        // prefetch next col chunk while gathers are in flight
        int jn = j + U;
        int cvN = node;
        if (jn < end) {                  // wave-uniform; after gather issue
            int idx = jn + lane;
            if (lane < U && idx < end) cvN = col[idx];
        }

        // exps (consume ssrcA; Hbf gathers still in flight)
        float e1 = 0.f, e2 = 0.f;
        if (EPEL == 2) {
            float a1 = sd + s1; a1 = (a1 >= 0.f) ? a1 : 0.2f * a1;
            float a2 = sd + s2; a2 = (a2 >= 0.f) ? a2 : 0.2f * a2;
            if (j + gb < end)         e1 = __expf(a1);
            if (j + gb + U / 2 < end) e2 = __expf(a2);
            dsum += e1 + e2;
        } else {
            float a1 = sd + s1; a1 = (a1 >= 0.f) ? a1 : 0.2f * a1;
            if (elane && j + gb < end) { e1 = __expf(a1); dsum += e1; }
        }

        // consume gathers (dead slots have zero weight)
        #pragma unroll
        for (int t = 0; t < NL; ++t) {
            int eidx = t * G + pp;
            float ex;
            if (EPEL == 2)
                ex = __shfl((t * G + G - 1 < U / 2) ? e1 : e2, (eidx & (U / 2 - 1)) * H + hh, 64);
            else
                ex = __shfl(e1, eidx * H + hh, 64);
            float f0 = __uint_as_float(hv[t].x << 16);
            float f1 = __uint_as_float(hv[t].x & 0xffff0000u);
            float f2 = __uint_as_float(hv[t].y << 16);
            float f3 = __uint_as_float(hv[t].y & 0xffff0000u);
            acc.x = fmaf(ex, f0, acc.x);
            acc.y = fmaf(ex, f1, acc.y);
            acc.z = fmaf(ex, f2, acc.z);
            acc.w = fmaf(ex, f3, acc.w);
        }
        cv = cvN;
    }

    // reduce dsum over edge-slot lanes (masked lanes contribute 0)
    #pragma unroll
    for (int off = H; off < 64; off <<= 1) dsum += __shfl_xor(dsum, off, 64);
    float den = __shfl(dsum, hh, 64);    // lane 'hh' holds head hh's full sum
    // reduce acc over gather-slot parities
    #pragma unroll
    for (int off = CP; off < 64; off <<= 1) {
        acc.x += __shfl_xor(acc.x, off, 64);
        acc.y += __shfl_xor(acc.y, off, 64);
        acc.z += __shfl_xor(acc.z, off, 64);
        acc.w += __shfl_xor(acc.w, off, 64);
    }
    if (lane < CP) {
        float inv = 1.f / den;
        float4 bv = ((const float4*)bias)[cp];
        float4 v;
        v.x = acc.x * inv + bv.x;
        v.y = acc.y * inv + bv.y;
        v.z = acc.z * inv + bv.z;
        v.w = acc.w * inv + bv.w;
        if (ELU_OUT) {
            v.x = (v.x > 0.f) ? v.x : expm1f(v.x);   // ELU(alpha=1)
            v.y = (v.y > 0.f) ? v.y : expm1f(v.y);
            v.z = (v.z > 0.f) ? v.z : expm1f(v.z);
            v.w = (v.w > 0.f) ? v.w : expm1f(v.w);
        }
        ((float4*)output)[(size_t)node * CP + cp] = v;
    }
}

// ---------------- launch ----------------

extern "C" void kernel_launch(void* const* d_in, const int* in_sizes, int n_in,
                              void* d_out, int out_size, void* d_ws, size_t ws_size,
                              hipStream_t stream) {
    const float* x    = (const float*)d_in[0];
    const int*   ei   = (const int*)d_in[1];
    const float* W1   = (const float*)d_in[2];
    const float* att1 = (const float*)d_in[3];
    const float* b1   = (const float*)d_in[4];
    const float* W2   = (const float*)d_in[5];
    const float* att2 = (const float*)d_in[6];
    const float* b2   = (const float*)d_in[7];
    const float* W3   = (const float*)d_in[8];
    const float* att3 = (const float*)d_in[9];
    const float* b3   = (const float*)d_in[10];
    float* out = (float*)d_out;

    char* p = (char*)d_ws;
    auto alloc = [&](size_t bytes) -> void* {
        void* r = (void*)p;
        p += (bytes + 255) & ~(size_t)255;
        return r;
    };
    int*   rowptr   = (int*)alloc((NN + 1) * sizeof(int));
    int*   deg      = (int*)alloc(NN * sizeof(int));
    int*   CntG     = (int*)alloc((size_t)CH * NN * sizeof(int));
    int*   partials = (int*)alloc(NB_SCAN * sizeof(int));
    int*   col      = (int*)alloc(EE * sizeof(int));
    float* sdst     = (float*)alloc((size_t)NN * 8 * sizeof(float));
    float* ssrcA    = (float*)alloc((size_t)NN * 8 * sizeof(float));
    uint2* Hbf      = (uint2*)alloc((size_t)NN * 16 * sizeof(uint2));
    float* Fb       = (float*)alloc((size_t)NN * 64 * sizeof(float));

    // --- CSR build front (3 dispatches) ---
    histL_k<<<CH * NR2, 256, 0, stream>>>(ei, CntG);
    combine_sum_k<<<NB_SCAN, 256, 0, stream>>>(CntG, deg, partials);
    scan_final<<<NB_SCAN, 256, 0, stream>>>(deg, partials, rowptr);

    // --- scatter || gemm1 (fused, union'd dynamic LDS) ---
    constexpr int SMEM = RSZ * (int)sizeof(int);   // 50000 B >= gemm's 48 KB
    sg1_k<<<SCAT_B + (NN + 63) / 64, 256, SMEM, stream>>>(ei, CntG, rowptr, col,
                                                          x, W1, att1, Hbf, ssrcA, sdst);

    // --- Layer 1 agg -> Fb ---
    agg_k<64, 8, 16, true><<<(NN + 3) / 4, 256, 0, stream>>>(rowptr, col, sdst, ssrcA, Hbf, b1, Fb);

    // --- Layer 2: Fb[N,64] -> h[N,64]; H=8, C=8; ELU out -> Fb ---
    gemm_tile<64, 64, 8, 64><<<(NN + 63) / 64, 256, 0, stream>>>(Fb, W2, att2, Hbf, ssrcA, sdst);
    agg_k<64, 8, 16, true><<<(NN + 3) / 4, 256, 0, stream>>>(rowptr, col, sdst, ssrcA, Hbf, b2, Fb);

    // --- Layer 3: Fb[N,64] -> h[N,32]; H=1, C=32; no ELU, f32 out -> d_out ---
    gemm_tile<64, 32, 1, 128><<<(NN + 127) / 128, 256, 0, stream>>>(Fb, W3, att3, Hbf, ssrcA, sdst);
    agg_k<32, 1, 32, false><<<(NN + 3) / 4, 256, 0, stream>>>(rowptr, col, sdst, ssrcA, Hbf, b3, out);
}